// Round 10
// baseline (194.029 us; speedup 1.0000x reference)
//
#include <hip/hip_runtime.h>
#include <hip/hip_bf16.h>
#include <cstdint>
#include <cstddef>

// Problem constants (B=4, N=256, D=32, H=512)
#define NB 4
#define NN 256
#define DD 32
#define HH 512

typedef __attribute__((ext_vector_type(8))) short short8;    // 8 bf16 (4 VGPRs) — MFMA A/B frag
typedef __attribute__((ext_vector_type(4))) float f32x4;     // 16x16 C/D frag
typedef __attribute__((ext_vector_type(16))) float f32x16;   // 32x32 C/D frag

// HW packed fp32->bf16 (RNE). a -> low 16, b -> high 16.
static __device__ __forceinline__ unsigned cvtpk(float a, float b) {
  unsigned r;
  asm("v_cvt_pk_bf16_f32 %0, %1, %2" : "=v"(r) : "v"(a), "v"(b));
  return r;
}
static __device__ __forceinline__ unsigned short f2bf1(float a) {
  return (unsigned short)(cvtpk(a, 0.f) & 0xffffu);
}

// build a bf16 A/B frag from 8 consecutive fp32 (two float4 loads already done)
static __device__ __forceinline__ short8 pack8(float4 a0, float4 a1) {
  union { unsigned u[4]; short8 s; } r;
  r.u[0] = cvtpk(a0.x, a0.y); r.u[1] = cvtpk(a0.z, a0.w);
  r.u[2] = cvtpk(a1.x, a1.y); r.u[3] = cvtpk(a1.z, a1.w);
  return r.s;
}

// ---------------------------------------------------------------------------
// prep (grid 1088x256):
//  blk < 1024 : T contraction, pure VALU fp32 (K=32 is too small for MFMA to
//    matter; this formulation has ZERO transposes):
//      blk = ntile*32 + mtile; block covers n in [ntile*512,+512),
//      bi in [mtile*32,+32).
//      Thread owns c = tid>>3, h0 = ntile*16 + (tid&7)*2 (two h-adjacent n).
//      W1 values live in 64 VGPRs, loaded coalesced: per a, lanes 0..7 read
//      consecutive float2 (64B line). z tile broadcast from LDS.
//      Tall[bi][h*32+c] = sum_a z[bi][a] * W1[(a*32+c)*512 + h]  (fp32 acc)
//  blk >= 1024: W2F builder — W2 (512x256) into 32x32x16 B-frag order:
//    slot f8 = w*4096 + hc*512 + s*128 + nt*64 + lane (8 bf16 each)
//    h = hc*64+s*16+(lane>>5)*8+e ; k2 = w*64+nt*32+(lane&31)
// ---------------------------------------------------------------------------
__global__ __launch_bounds__(256) void prep(const float* __restrict__ z,
                                            const float* __restrict__ W1,
                                            const float* __restrict__ W2,
                                            unsigned short* __restrict__ W2F,
                                            unsigned short* __restrict__ Tall) {
  const int blk = blockIdx.x;
  const int tid = threadIdx.x;
  if (blk < 1024) {
    __shared__ float z_s[32 * 32];
    const int ntile = blk >> 5, mtile = blk & 31;
    const int bibase = mtile * 32;

    // stage z tile (32 bi x 32 a = 4KB contiguous)
    ((float4*)z_s)[tid] = ((const float4*)(z + (size_t)bibase * 32))[tid];

    // W1 columns into registers, coalesced (8 lanes = 64B contiguous)
    const int c = tid >> 3;
    const int h0 = (tid & 7) * 2;                 // h relative to ntile*16
    const float* wp = W1 + (size_t)c * 512 + ntile * 16 + h0;
    float2 w1r[32];
    #pragma unroll
    for (int a = 0; a < 32; ++a)
      w1r[a] = *(const float2*)(wp + (size_t)a * 16384);
    __syncthreads();

    // outputs: n0 = (ntile*16+h0)*32 + c and n0 + 32
    unsigned short* op = Tall + (size_t)bibase * 16384 + (ntile * 16 + h0) * 32 + c;
    const float4* z4 = (const float4*)z_s;
    for (int bi = 0; bi < 32; ++bi) {
      float a0 = 0.f, a1 = 0.f;
      #pragma unroll
      for (int q = 0; q < 8; ++q) {
        float4 zz = z4[bi * 8 + q];
        a0 += zz.x * w1r[q * 4 + 0].x; a1 += zz.x * w1r[q * 4 + 0].y;
        a0 += zz.y * w1r[q * 4 + 1].x; a1 += zz.y * w1r[q * 4 + 1].y;
        a0 += zz.z * w1r[q * 4 + 2].x; a1 += zz.z * w1r[q * 4 + 2].y;
        a0 += zz.w * w1r[q * 4 + 3].x; a1 += zz.w * w1r[q * 4 + 3].y;
      }
      op[0]  = f2bf1(a0);
      op[32] = f2bf1(a1);     // next h -> +32 elements (64B)
      op += 16384;
    }
  } else {
    int f8 = (blk - 1024) * 256 + tid;    // frag-slot index (8 elems each)
    int lane = f8 & 63;
    int nt = (f8 >> 6) & 1, s = (f8 >> 7) & 3, hc = (f8 >> 9) & 7, w = (f8 >> 12) & 3;
    int k2 = w * 64 + nt * 32 + (lane & 31);
    int hb = hc * 64 + s * 16 + (lane >> 5) * 8;
    float v[8];
    #pragma unroll
    for (int e = 0; e < 8; ++e) v[e] = W2[(hb + e) * 256 + k2];
    uint4 p;
    p.x = cvtpk(v[0], v[1]); p.y = cvtpk(v[2], v[3]);
    p.z = cvtpk(v[4], v[5]); p.w = cvtpk(v[6], v[7]);
    ((uint4*)W2F)[f8] = p;
  }
}

// ---------------------------------------------------------------------------
// fused: UNCHANGED from R9 (clean attribution for the prep experiment).
// block = (b,i,jt of 64 j), 256 threads / 4 waves. H split into 2 halves:
//   phase1: 4 waves fill h1s[64j][256h] (16x16x32, b1 as C-operand)
//   phase2: 16 u-steps, 4 MFMA 32x32x16/wave/step; bf 3-deep, af 2-deep.
// ---------------------------------------------------------------------------
__global__ __launch_bounds__(256) void fused(const unsigned short* __restrict__ Tall,
                                             const unsigned short* __restrict__ W2F,
                                             const float* __restrict__ z,
                                             const float* __restrict__ b1,
                                             const float* __restrict__ b2,
                                             const float* __restrict__ W3,
                                             const float* __restrict__ b3,
                                             const float* __restrict__ motif,
                                             float* __restrict__ out) {
  __shared__ unsigned short h1s[64 * 264];   // [j][h_local], stride 264
  __shared__ float red[256];

  const int tid = threadIdx.x;
  const int w = tid >> 6, lane = tid & 63;
  const int quad = lane >> 4, l16 = lane & 15;
  const int L = lane >> 5, c32 = lane & 31;

  // XCD swizzle: 4 jt-siblings of one bi land on the same XCD (bx % 8 equal)
  const int bx = blockIdx.x;
  const int jt = (bx >> 3) & 3;
  const int bi = (bx & 7) | ((bx >> 5) << 3);   // b*256 + i
  const int b = bi >> 8, i = bi & 255;
  const int jbase = jt * 64;

  // phase-1 z frags (16x16x32 B-operand) from fp32 z: [k=c=quad*8+e][n=j=l16]
  short8 zfr[4];
  #pragma unroll
  for (int nt = 0; nt < 4; ++nt) {
    const float* zr = z + (size_t)(b * 256 + jbase + nt * 16 + l16) * 32 + quad * 8;
    float4 a0 = *(const float4*)(zr);
    float4 a1 = *(const float4*)(zr + 4);
    zfr[nt] = pack8(a0, a1);
  }

  // epilogue constants: this wave owns k2 in [64w, 64w+64)
  float b2v[2], w3v[2];
  #pragma unroll
  for (int nt = 0; nt < 2; ++nt) {
    int k2 = w * 64 + nt * 32 + c32;
    b2v[nt] = b2[k2];
    w3v[nt] = W3[k2];
  }

  f32x16 acc[2][2];
  #pragma unroll
  for (int mt = 0; mt < 2; ++mt)
    #pragma unroll
    for (int nt = 0; nt < 2; ++nt)
      acc[mt][nt] = (f32x16){0.f,0.f,0.f,0.f,0.f,0.f,0.f,0.f,
                             0.f,0.f,0.f,0.f,0.f,0.f,0.f,0.f};

  const unsigned short* Tbase = Tall + (size_t)bi * 16384 + (w * 16 + l16) * 32 + quad * 8;
  const unsigned short* Wp = W2F + w * 32768 + lane * 8;
  const float* b1base = b1 + w * 16 + quad * 4;

  #pragma unroll
  for (int half = 0; half < 2; ++half) {
    // ---- phase 1: wave w fills h-rows {q*64 + w*16 + [0,16)} x 64 j
    short8 tfr[4];
    #pragma unroll
    for (int q = 0; q < 4; ++q)
      tfr[q] = *(const short8*)(Tbase + (half * 4 + q) * 2048);
    #pragma unroll
    for (int q = 0; q < 4; ++q) {
      float4 b1f = *(const float4*)(b1base + (half * 4 + q) * 64);
      f32x4 cin = {b1f.x, b1f.y, b1f.z, b1f.w};
      #pragma unroll
      for (int nt = 0; nt < 4; ++nt) {
        f32x4 d = __builtin_amdgcn_mfma_f32_16x16x32_bf16(tfr[q], zfr[nt], cin, 0, 0, 0);
        // D: row = quad*4+r -> h_rel, col = l16 -> j within nt's 16
        uint2 p;
        p.x = cvtpk(fmaxf(d[0], 0.f), fmaxf(d[1], 0.f));
        p.y = cvtpk(fmaxf(d[2], 0.f), fmaxf(d[3], 0.f));
        *(uint2*)&h1s[(nt * 16 + l16) * 264 + q * 64 + w * 16 + quad * 4] = p;
      }
    }
    __syncthreads();

    // ---- phase 2: 16 u-steps (h_local = u*16 + L*8); bf 3-deep, af 2-deep
    const unsigned short* Wh = Wp + half * 16384;
    const unsigned short* h1r = &h1s[c32 * 264 + L * 8];
    short8 bfp[3][2], afp[2][2];
    #pragma unroll
    for (int p = 0; p < 3; ++p) {
      bfp[p][0] = *(const short8*)(Wh + p * 1024);
      bfp[p][1] = *(const short8*)(Wh + p * 1024 + 512);
    }
    afp[0][0] = *(const short8*)(h1r);
    afp[0][1] = *(const short8*)(h1r + 32 * 264);
    afp[1][0] = *(const short8*)(h1r + 16);
    afp[1][1] = *(const short8*)(h1r + 32 * 264 + 16);
    #pragma unroll
    for (int u = 0; u < 16; ++u) {
      const int cur = u & 1, bq = u % 3;
      short8 a0 = afp[cur][0], a1 = afp[cur][1];
      short8 b0 = bfp[bq][0], b1q = bfp[bq][1];
      if (u < 14) {
        afp[cur][0] = *(const short8*)(h1r + (u + 2) * 16);
        afp[cur][1] = *(const short8*)(h1r + 32 * 264 + (u + 2) * 16);
      }
      if (u < 13) {
        bfp[bq][0] = *(const short8*)(Wh + (u + 3) * 1024);
        bfp[bq][1] = *(const short8*)(Wh + (u + 3) * 1024 + 512);
      }
      acc[0][0] = __builtin_amdgcn_mfma_f32_32x32x16_bf16(a0, b0, acc[0][0], 0, 0, 0);
      acc[0][1] = __builtin_amdgcn_mfma_f32_32x32x16_bf16(a0, b1q, acc[0][1], 0, 0, 0);
      acc[1][0] = __builtin_amdgcn_mfma_f32_32x32x16_bf16(a1, b0, acc[1][0], 0, 0, 0);
      acc[1][1] = __builtin_amdgcn_mfma_f32_32x32x16_bf16(a1, b1q, acc[1][1], 0, 0, 0);
    }
    if (half == 0) __syncthreads();   // protect h1s before half-1 overwrites
  }

  // ---- epilogue: relu(h2+b2) . W3, reduce over k2 (32 lanes), then 4 waves
  float pr[2][16];
  #pragma unroll
  for (int mt = 0; mt < 2; ++mt)
    #pragma unroll
    for (int reg = 0; reg < 16; ++reg) {
      float s = 0.f;
      #pragma unroll
      for (int nt = 0; nt < 2; ++nt) {
        float v = acc[mt][nt][reg] + b2v[nt];
        v = v > 0.f ? v : 0.f;
        s += v * w3v[nt];
      }
      s += __shfl_xor(s, 1);
      s += __shfl_xor(s, 2);
      s += __shfl_xor(s, 4);
      s += __shfl_xor(s, 8);
      s += __shfl_xor(s, 16);
      pr[mt][reg] = s;
    }
  if (c32 == 0) {
    #pragma unroll
    for (int mt = 0; mt < 2; ++mt)
      #pragma unroll
      for (int g = 0; g < 4; ++g) {
        float4 vv = {pr[mt][g * 4 + 0], pr[mt][g * 4 + 1],
                     pr[mt][g * 4 + 2], pr[mt][g * 4 + 3]};
        // j_rel = mt*32 + 8g + 4L + r
        *(float4*)&red[w * 64 + mt * 32 + g * 8 + L * 4] = vv;
      }
  }
  __syncthreads();
  if (tid < 64) {
    int j = tid;
    float logit = red[j] + red[64 + j] + red[128 + j] + red[192 + j] + b3[0];
    float mm = motif[b * 256 + i] * motif[b * 256 + jbase + j];
    logit *= mm;
    float map = 1.f / (1.f + expf(-logit));
    size_t idx = (size_t)(b * 256 + i) * 256 + jbase + j;
    out[idx] = map;                           // contact_map
    out[(size_t)NB * NN * NN + idx] = logit;  // contact_logits
  }
}

// ---------------------------------------------------------------------------
extern "C" void kernel_launch(void* const* d_in, const int* in_sizes, int n_in,
                              void* d_out, int out_size, void* d_ws, size_t ws_size,
                              hipStream_t stream) {
  const float* z     = (const float*)d_in[0];
  const float* motif = (const float*)d_in[1];
  // d_in[2] residue_mask: all-ones, unused by the reference computation
  const float* W1 = (const float*)d_in[3];
  const float* b1 = (const float*)d_in[4];
  const float* W2 = (const float*)d_in[5];
  const float* b2 = (const float*)d_in[6];
  const float* W3 = (const float*)d_in[7];
  const float* b3 = (const float*)d_in[8];
  float* out = (float*)d_out;

  char* ws = (char*)d_ws;
  unsigned short* Tall = (unsigned short*)ws;                       // 32 MiB
  unsigned short* W2F  = (unsigned short*)(ws + 33554432);          // 256 KiB

  prep<<<1088, 256, 0, stream>>>(z, W1, W2, W2F, Tall);
  fused<<<4096, 256, 0, stream>>>(Tall, W2F, z, b1, b2, W3, b3, motif, out);
}

// Round 11
// 186.041 us; speedup vs baseline: 1.0429x; 1.0429x over previous
//
#include <hip/hip_runtime.h>
#include <hip/hip_bf16.h>
#include <cstdint>
#include <cstddef>

// Problem constants (B=4, N=256, D=32, H=512)
#define NB 4
#define NN 256
#define DD 32
#define HH 512

typedef __attribute__((ext_vector_type(8))) short short8;    // 8 bf16 (4 VGPRs) — MFMA A/B frag
typedef __attribute__((ext_vector_type(4))) float f32x4;     // 16x16 C/D frag
typedef __attribute__((ext_vector_type(16))) float f32x16;   // 32x32 C/D frag

// HW packed fp32->bf16 (RNE). a -> low 16, b -> high 16.
static __device__ __forceinline__ unsigned cvtpk(float a, float b) {
  unsigned r;
  asm("v_cvt_pk_bf16_f32 %0, %1, %2" : "=v"(r) : "v"(a), "v"(b));
  return r;
}
static __device__ __forceinline__ unsigned short f2bf1(float a) {
  return (unsigned short)(cvtpk(a, 0.f) & 0xffffu);
}

// build a bf16 A/B frag from 8 consecutive fp32 (two float4 loads already done)
static __device__ __forceinline__ short8 pack8(float4 a0, float4 a1) {
  union { unsigned u[4]; short8 s; } r;
  r.u[0] = cvtpk(a0.x, a0.y); r.u[1] = cvtpk(a0.z, a0.w);
  r.u[2] = cvtpk(a1.x, a1.y); r.u[3] = cvtpk(a1.z, a1.w);
  return r.s;
}

// ---------------------------------------------------------------------------
// prep (grid 576x256):
//  blk < 512 : T-GEMM block (nblk = blk>>4 of 32, mgrp = blk&15 of 16).
//    Covers n in [nblk*512,+512) (h in [nblk*16,+16), all 32 c), bi in
//    [mgrp*64,+64). K=32 (a) in ONE 16x16x32 MFMA step.
//    Step 1: stage W1 slice (1024 dd-rows x 16 h fp32) -> LDS bf16 in
//      B-frag order. Global reads: 4 lanes per dd-row (float4 each) -> 64 B
//      contiguous segments, full line utilization. Frag col mapping uses the
//      n-interleave  n_local = w2*128 + l16*8 + nt  so that each lane's 8
//      nt-results are 8 CONSECUTIVE n -> b128 Tall stores.
//    Step 2: 4 waves x 32 MFMA16 (mt 4 x nt 8, split in 2 mt-groups for VGPR),
//      A = z (fp32->bf16 in regs), B from LDS; store D as packed uint4:
//      Tall[bi][nblk*512 + w2*128 + l16*8 + nt], fully coalesced.
//  blk >= 512: W2F builder — W2 (512x256) into 32x32x16 B-frag order:
//    slot f8 = w*4096 + hc*512 + s*128 + nt*64 + lane (8 bf16 each)
//    h = hc*64+s*16+(lane>>5)*8+e ; k2 = w*64+nt*32+(lane&31)
// ---------------------------------------------------------------------------
__global__ __launch_bounds__(256) void prep(const float* __restrict__ z,
                                            const float* __restrict__ W1,
                                            const float* __restrict__ W2,
                                            unsigned short* __restrict__ W2F,
                                            unsigned short* __restrict__ Tall) {
  const int blk = blockIdx.x;
  const int tid = threadIdx.x;
  if (blk < 512) {
    __shared__ unsigned short w1s[16384];   // 32 KB: [w2][nt][lane][e]
    const int nblk = blk >> 4, mgrp = blk & 15;
    const int bibase = mgrp * 64;

    // ---- stage W1 slice: 16 rounds x (1 coalesced float4 + 4 b16 LDS writes)
    #pragma unroll
    for (int r = 0; r < 16; ++r) {
      int task = r * 256 + tid;
      int row = task >> 2;                  // dd = a*32 + c   (0..1023)
      int hq = task & 3;                    // which 4-float group of the 16 h
      float4 v = *(const float4*)(W1 + (size_t)row * 512 + nblk * 16 + hq * 4);
      int a = row >> 5, c = row & 31;
      int quad = a >> 3, e = a & 7;
      float hv[4] = {v.x, v.y, v.z, v.w};
      #pragma unroll
      for (int vv = 0; vv < 4; ++vv) {
        int hl = hq * 4 + vv;
        int nl = hl * 32 + c;               // n_local in [0,512)
        int w2 = nl >> 7, r7 = nl & 127;
        int l16 = r7 >> 3, nt = r7 & 7;
        w1s[((w2 * 8 + nt) * 64 + quad * 16 + l16) * 8 + e] = f2bf1(hv[vv]);
      }
    }
    __syncthreads();

    const int w2 = tid >> 6, lane = tid & 63;
    const int quad = lane >> 4, l16 = lane & 15;

    short8 bfr[8];
    #pragma unroll
    for (int nt = 0; nt < 8; ++nt)
      bfr[nt] = *(const short8*)&w1s[((w2 * 8 + nt) * 64 + lane) * 8];

    const int ncol = nblk * 512 + w2 * 128 + l16 * 8;
    #pragma unroll
    for (int mtg = 0; mtg < 2; ++mtg) {     // 2 mt-groups of 2 -> lower VGPR
      short8 afr[2];
      #pragma unroll
      for (int mi = 0; mi < 2; ++mi) {
        const float* zr = z + (size_t)(bibase + (mtg * 2 + mi) * 16 + l16) * 32 + quad * 8;
        float4 a0 = *(const float4*)(zr);
        float4 a1 = *(const float4*)(zr + 4);
        afr[mi] = pack8(a0, a1);
      }
      f32x4 d[2][8];
      #pragma unroll
      for (int mi = 0; mi < 2; ++mi)
        #pragma unroll
        for (int nt = 0; nt < 8; ++nt)
          d[mi][nt] = __builtin_amdgcn_mfma_f32_16x16x32_bf16(
              afr[mi], bfr[nt], (f32x4){0.f, 0.f, 0.f, 0.f}, 0, 0, 0);
      #pragma unroll
      for (int mi = 0; mi < 2; ++mi)
        #pragma unroll
        for (int r = 0; r < 4; ++r) {
          size_t rowoff = (size_t)(bibase + (mtg * 2 + mi) * 16 + quad * 4 + r) * 16384;
          uint4 p;
          p.x = cvtpk(d[mi][0][r], d[mi][1][r]);
          p.y = cvtpk(d[mi][2][r], d[mi][3][r]);
          p.z = cvtpk(d[mi][4][r], d[mi][5][r]);
          p.w = cvtpk(d[mi][6][r], d[mi][7][r]);
          *(uint4*)&Tall[rowoff + ncol] = p;
        }
    }
  } else {
    int f8 = (blk - 512) * 256 + tid;       // frag-slot index (8 elems each)
    int lane = f8 & 63;
    int nt = (f8 >> 6) & 1, s = (f8 >> 7) & 3, hc = (f8 >> 9) & 7, w = (f8 >> 12) & 3;
    int k2 = w * 64 + nt * 32 + (lane & 31);
    int hb = hc * 64 + s * 16 + (lane >> 5) * 8;
    float v[8];
    #pragma unroll
    for (int e = 0; e < 8; ++e) v[e] = W2[(hb + e) * 256 + k2];
    uint4 p;
    p.x = cvtpk(v[0], v[1]); p.y = cvtpk(v[2], v[3]);
    p.z = cvtpk(v[4], v[5]); p.w = cvtpk(v[6], v[7]);
    ((uint4*)W2F)[f8] = p;
  }
}

// ---------------------------------------------------------------------------
// fused: UNCHANGED from R9 (clean attribution for the prep experiment).
// block = (b,i,jt of 64 j), 256 threads / 4 waves. H split into 2 halves:
//   phase1: 4 waves fill h1s[64j][256h] (16x16x32, b1 as C-operand)
//   phase2: 16 u-steps, 4 MFMA 32x32x16/wave/step; bf 3-deep, af 2-deep.
// ---------------------------------------------------------------------------
__global__ __launch_bounds__(256) void fused(const unsigned short* __restrict__ Tall,
                                             const unsigned short* __restrict__ W2F,
                                             const float* __restrict__ z,
                                             const float* __restrict__ b1,
                                             const float* __restrict__ b2,
                                             const float* __restrict__ W3,
                                             const float* __restrict__ b3,
                                             const float* __restrict__ motif,
                                             float* __restrict__ out) {
  __shared__ unsigned short h1s[64 * 264];   // [j][h_local], stride 264
  __shared__ float red[256];

  const int tid = threadIdx.x;
  const int w = tid >> 6, lane = tid & 63;
  const int quad = lane >> 4, l16 = lane & 15;
  const int L = lane >> 5, c32 = lane & 31;

  // XCD swizzle: 4 jt-siblings of one bi land on the same XCD (bx % 8 equal)
  const int bx = blockIdx.x;
  const int jt = (bx >> 3) & 3;
  const int bi = (bx & 7) | ((bx >> 5) << 3);   // b*256 + i
  const int b = bi >> 8, i = bi & 255;
  const int jbase = jt * 64;

  // phase-1 z frags (16x16x32 B-operand) from fp32 z: [k=c=quad*8+e][n=j=l16]
  short8 zfr[4];
  #pragma unroll
  for (int nt = 0; nt < 4; ++nt) {
    const float* zr = z + (size_t)(b * 256 + jbase + nt * 16 + l16) * 32 + quad * 8;
    float4 a0 = *(const float4*)(zr);
    float4 a1 = *(const float4*)(zr + 4);
    zfr[nt] = pack8(a0, a1);
  }

  // epilogue constants: this wave owns k2 in [64w, 64w+64)
  float b2v[2], w3v[2];
  #pragma unroll
  for (int nt = 0; nt < 2; ++nt) {
    int k2 = w * 64 + nt * 32 + c32;
    b2v[nt] = b2[k2];
    w3v[nt] = W3[k2];
  }

  f32x16 acc[2][2];
  #pragma unroll
  for (int mt = 0; mt < 2; ++mt)
    #pragma unroll
    for (int nt = 0; nt < 2; ++nt)
      acc[mt][nt] = (f32x16){0.f,0.f,0.f,0.f,0.f,0.f,0.f,0.f,
                             0.f,0.f,0.f,0.f,0.f,0.f,0.f,0.f};

  const unsigned short* Tbase = Tall + (size_t)bi * 16384 + (w * 16 + l16) * 32 + quad * 8;
  const unsigned short* Wp = W2F + w * 32768 + lane * 8;
  const float* b1base = b1 + w * 16 + quad * 4;

  #pragma unroll
  for (int half = 0; half < 2; ++half) {
    // ---- phase 1: wave w fills h-rows {q*64 + w*16 + [0,16)} x 64 j
    short8 tfr[4];
    #pragma unroll
    for (int q = 0; q < 4; ++q)
      tfr[q] = *(const short8*)(Tbase + (half * 4 + q) * 2048);
    #pragma unroll
    for (int q = 0; q < 4; ++q) {
      float4 b1f = *(const float4*)(b1base + (half * 4 + q) * 64);
      f32x4 cin = {b1f.x, b1f.y, b1f.z, b1f.w};
      #pragma unroll
      for (int nt = 0; nt < 4; ++nt) {
        f32x4 d = __builtin_amdgcn_mfma_f32_16x16x32_bf16(tfr[q], zfr[nt], cin, 0, 0, 0);
        // D: row = quad*4+r -> h_rel, col = l16 -> j within nt's 16
        uint2 p;
        p.x = cvtpk(fmaxf(d[0], 0.f), fmaxf(d[1], 0.f));
        p.y = cvtpk(fmaxf(d[2], 0.f), fmaxf(d[3], 0.f));
        *(uint2*)&h1s[(nt * 16 + l16) * 264 + q * 64 + w * 16 + quad * 4] = p;
      }
    }
    __syncthreads();

    // ---- phase 2: 16 u-steps (h_local = u*16 + L*8); bf 3-deep, af 2-deep
    const unsigned short* Wh = Wp + half * 16384;
    const unsigned short* h1r = &h1s[c32 * 264 + L * 8];
    short8 bfp[3][2], afp[2][2];
    #pragma unroll
    for (int p = 0; p < 3; ++p) {
      bfp[p][0] = *(const short8*)(Wh + p * 1024);
      bfp[p][1] = *(const short8*)(Wh + p * 1024 + 512);
    }
    afp[0][0] = *(const short8*)(h1r);
    afp[0][1] = *(const short8*)(h1r + 32 * 264);
    afp[1][0] = *(const short8*)(h1r + 16);
    afp[1][1] = *(const short8*)(h1r + 32 * 264 + 16);
    #pragma unroll
    for (int u = 0; u < 16; ++u) {
      const int cur = u & 1, bq = u % 3;
      short8 a0 = afp[cur][0], a1 = afp[cur][1];
      short8 b0 = bfp[bq][0], b1q = bfp[bq][1];
      if (u < 14) {
        afp[cur][0] = *(const short8*)(h1r + (u + 2) * 16);
        afp[cur][1] = *(const short8*)(h1r + 32 * 264 + (u + 2) * 16);
      }
      if (u < 13) {
        bfp[bq][0] = *(const short8*)(Wh + (u + 3) * 1024);
        bfp[bq][1] = *(const short8*)(Wh + (u + 3) * 1024 + 512);
      }
      acc[0][0] = __builtin_amdgcn_mfma_f32_32x32x16_bf16(a0, b0, acc[0][0], 0, 0, 0);
      acc[0][1] = __builtin_amdgcn_mfma_f32_32x32x16_bf16(a0, b1q, acc[0][1], 0, 0, 0);
      acc[1][0] = __builtin_amdgcn_mfma_f32_32x32x16_bf16(a1, b0, acc[1][0], 0, 0, 0);
      acc[1][1] = __builtin_amdgcn_mfma_f32_32x32x16_bf16(a1, b1q, acc[1][1], 0, 0, 0);
    }
    if (half == 0) __syncthreads();   // protect h1s before half-1 overwrites
  }

  // ---- epilogue: relu(h2+b2) . W3, reduce over k2 (32 lanes), then 4 waves
  float pr[2][16];
  #pragma unroll
  for (int mt = 0; mt < 2; ++mt)
    #pragma unroll
    for (int reg = 0; reg < 16; ++reg) {
      float s = 0.f;
      #pragma unroll
      for (int nt = 0; nt < 2; ++nt) {
        float v = acc[mt][nt][reg] + b2v[nt];
        v = v > 0.f ? v : 0.f;
        s += v * w3v[nt];
      }
      s += __shfl_xor(s, 1);
      s += __shfl_xor(s, 2);
      s += __shfl_xor(s, 4);
      s += __shfl_xor(s, 8);
      s += __shfl_xor(s, 16);
      pr[mt][reg] = s;
    }
  if (c32 == 0) {
    #pragma unroll
    for (int mt = 0; mt < 2; ++mt)
      #pragma unroll
      for (int g = 0; g < 4; ++g) {
        float4 vv = {pr[mt][g * 4 + 0], pr[mt][g * 4 + 1],
                     pr[mt][g * 4 + 2], pr[mt][g * 4 + 3]};
        // j_rel = mt*32 + 8g + 4L + r
        *(float4*)&red[w * 64 + mt * 32 + g * 8 + L * 4] = vv;
      }
  }
  __syncthreads();
  if (tid < 64) {
    int j = tid;
    float logit = red[j] + red[64 + j] + red[128 + j] + red[192 + j] + b3[0];
    float mm = motif[b * 256 + i] * motif[b * 256 + jbase + j];
    logit *= mm;
    float map = 1.f / (1.f + expf(-logit));
    size_t idx = (size_t)(b * 256 + i) * 256 + jbase + j;
    out[idx] = map;                           // contact_map
    out[(size_t)NB * NN * NN + idx] = logit;  // contact_logits
  }
}

// ---------------------------------------------------------------------------
extern "C" void kernel_launch(void* const* d_in, const int* in_sizes, int n_in,
                              void* d_out, int out_size, void* d_ws, size_t ws_size,
                              hipStream_t stream) {
  const float* z     = (const float*)d_in[0];
  const float* motif = (const float*)d_in[1];
  // d_in[2] residue_mask: all-ones, unused by the reference computation
  const float* W1 = (const float*)d_in[3];
  const float* b1 = (const float*)d_in[4];
  const float* W2 = (const float*)d_in[5];
  const float* b2 = (const float*)d_in[6];
  const float* W3 = (const float*)d_in[7];
  const float* b3 = (const float*)d_in[8];
  float* out = (float*)d_out;

  char* ws = (char*)d_ws;
  unsigned short* Tall = (unsigned short*)ws;                       // 32 MiB
  unsigned short* W2F  = (unsigned short*)(ws + 33554432);          // 256 KiB

  prep<<<576, 256, 0, stream>>>(z, W1, W2, W2F, Tall);
  fused<<<4096, 256, 0, stream>>>(Tall, W2F, z, b1, b2, W3, b3, motif, out);
}